// Round 3
// baseline (248.172 us; speedup 1.0000x reference)
//
#include <hip/hip_runtime.h>

#define T_STEPS 65536
#define NZ 64
#define NH1 128
#define NH2 64
#define NEDGE 512
#define NCHUNK 8192
#define CL 8            // timesteps per chunk (T_STEPS / NCHUNK)
#define NSUPER 128
#define SUP_L 64        // chunks per super (NCHUNK / NSUPER)

// ---- ws layout (bytes)
#define ADJ_OFF        0          // 64 * u64
#define BASE1_OFF      512        // 128 * f64
#define W1T_OFF        1536       // 128 * f64
#define NBRT_OFF       2560       // 64*64 u8, transposed [k][z]
#define MAXDEG_OFF     6656       // i32
#define CHUNKSTATE_OFF 6720       // NCHUNK * i32 = 32768 (ends 39488)
#define W2D_OFF        40960     // 128*64 f64 = 65536
#define W3TD_OFF       106496    // 64*64 f64 (transposed [z][j]) = 32768
#define B2D_OFF        139264    // 64 f64
#define B3D_OFF        139776    // 64 f64
#define LG64_OFF       140288    // T*64 f64 = 33,554,432
#define WS_NEED        (LG64_OFF + (size_t)T_STEPS * NZ * 8)

// ---- d_out used as scratch before finalize overwrites it (deterministic)
#define CHUNKG_DOUT    0          // NCHUNK*64 u8 = 524288
#define SUPERS_DOUT    524288     // NSUPER*64 u8 = 8192
#define SUPSTATE_DOUT  532480     // NSUPER * i32 = 512

typedef unsigned long long ull;

// ---------------------------------------------------------------------------
// K1: adjacency bitmasks, padded neighbor lists, f64 weight precompute
// (base1/w1t, W2 f64, W3 f64 transposed, b2/b3 f64). Single block.
// ---------------------------------------------------------------------------
__global__ void prep_kernel(const float* __restrict__ pa,
                            const int* __restrict__ edges,
                            const float* __restrict__ W1,
                            const float* __restrict__ b1,
                            const float* __restrict__ W2,
                            const float* __restrict__ b2,
                            const float* __restrict__ W3,
                            const float* __restrict__ b3,
                            unsigned char* ws) {
  ull* adj = (ull*)(ws + ADJ_OFF);
  double* base1 = (double*)(ws + BASE1_OFF);
  double* w1t   = (double*)(ws + W1T_OFF);
  unsigned char* nbrT = ws + NBRT_OFF;
  double* W2d  = (double*)(ws + W2D_OFF);
  double* W3td = (double*)(ws + W3TD_OFF);
  double* b2d  = (double*)(ws + B2D_OFF);
  double* b3d  = (double*)(ws + B3D_OFF);
  __shared__ int smax;
  __shared__ int sdeg[NZ];
  int tid = threadIdx.x;
  if (tid == 0) smax = 0;
  if (tid < NZ) adj[tid] = 0ull;
  __syncthreads();
  if (tid < NEDGE) {
    int e0 = edges[tid];
    int e1 = edges[NEDGE + tid];
    atomicOr(&adj[e0], 1ull << e1);
    atomicOr(&adj[e1], 1ull << e0);
  }
  if (tid < NZ) atomicOr(&adj[tid], 1ull << tid);  // self loops
  if (tid < NH1) {
    double acc = (double)b1[tid];
    for (int d = 0; d < 64; ++d)
      acc += (double)pa[d] * (double)W1[d * NH1 + tid];
    base1[tid] = acc;
    w1t[tid] = (double)W1[64 * NH1 + tid];
  }
  for (int i = tid; i < NH1 * NH2; i += 512) W2d[i] = (double)W2[i];
  for (int i = tid; i < NH2 * NZ; i += 512) {
    int j = i >> 6, z = i & 63;
    W3td[z * 64 + j] = (double)W3[i];
  }
  if (tid < NH2) b2d[tid] = (double)b2[tid];
  if (tid < NZ)  b3d[tid] = (double)b3[tid];
  __syncthreads();
  if (tid < NZ) {
    ull m = adj[tid];
    int deg = 0;
    while (m) {
      int j = __builtin_ctzll(m);
      m &= m - 1;
      nbrT[deg * 64 + tid] = (unsigned char)j;
      ++deg;
    }
    sdeg[tid] = deg;
    atomicMax(&smax, deg);
  }
  __syncthreads();
  if (tid < NZ) {
    int deg = sdeg[tid];
    unsigned char j0 = nbrT[0 * 64 + tid];  // deg >= 1 (self loop)
    for (int k = deg; k < smax; ++k) nbrT[k * 64 + tid] = j0;
  }
  if (tid == 0) *(int*)(ws + MAXDEG_OFF) = smax;
}

// ---------------------------------------------------------------------------
// K2: per-lane-timestep MLP. lane = timestep; acc[64] f64 held in VGPRs with
// static indexing; weights consumed as uniform scalar loads (f64, prepped).
// Output transposed to coalesced [t][z] via a padded per-wave LDS tile.
// One wave per block (tile is 33.3KB, static-LDS cap is 64KB).
// ---------------------------------------------------------------------------
__global__ __launch_bounds__(64, 1) void mlp_kernel(
    const float* __restrict__ times,
    const unsigned char* __restrict__ ws_ro,
    double* __restrict__ lg64) {
  __shared__ double tile[64 * 65];
  const double* __restrict__ base1 = (const double*)(ws_ro + BASE1_OFF);
  const double* __restrict__ w1t   = (const double*)(ws_ro + W1T_OFF);
  const double* __restrict__ W2d   = (const double*)(ws_ro + W2D_OFF);
  const double* __restrict__ W3td  = (const double*)(ws_ro + W3TD_OFF);
  const double* __restrict__ b2d   = (const double*)(ws_ro + B2D_OFF);
  const double* __restrict__ b3d   = (const double*)(ws_ro + B3D_OFF);

  int lane = threadIdx.x;
  int t0 = blockIdx.x * 64;
  double tv = (double)times[t0 + lane];

  double acc[64];
  #pragma unroll
  for (int j = 0; j < 64; ++j) acc[j] = b2d[j];

  #pragma unroll 2
  for (int h = 0; h < NH1; ++h) {
    double a = fma(tv, w1t[h], base1[h]);
    a = a > 0.0 ? a : 0.0;
    const double* __restrict__ row = W2d + h * 64;
    #pragma unroll
    for (int j = 0; j < 64; ++j) acc[j] = fma(a, row[j], acc[j]);
  }
  #pragma unroll
  for (int j = 0; j < 64; ++j) acc[j] = acc[j] > 0.0 ? acc[j] : 0.0;

  for (int z = 0; z < 64; ++z) {
    double lg = b3d[z];
    const double* __restrict__ row = W3td + z * 64;
    #pragma unroll
    for (int j = 0; j < 64; ++j) lg = fma(acc[j], row[j], lg);
    tile[lane * 65 + z] = lg;  // [t_local][z], padded
  }
  // wave-private tile: compiler inserts the lgkm wait; no barrier needed
  for (int t = 0; t < 64; ++t)
    lg64[(size_t)(t0 + t) * 64 + lane] = tile[t * 65 + lane];
}

// ---------------------------------------------------------------------------
// K3: per-chunk composed transition tables (unchanged from round 2).
// ---------------------------------------------------------------------------
__global__ __launch_bounds__(256) void chunk_tables_kernel(
    const double* __restrict__ lg64, const unsigned char* __restrict__ ws_ro,
    unsigned char* __restrict__ chunkG) {
  __shared__ double lgs[4][CL][64];
  __shared__ unsigned char nbrTs[4096];
  int tid = threadIdx.x, lane = tid & 63, wv = tid >> 6;
  for (int i = tid; i < 1024; i += 256)
    ((unsigned int*)nbrTs)[i] = ((const unsigned int*)(ws_ro + NBRT_OFF))[i];
  const int maxdeg = *(const int*)(ws_ro + MAXDEG_OFF);
  ull mask = ((const ull*)(ws_ro + ADJ_OFF))[lane];
  int c = blockIdx.x * 4 + wv;
  size_t tb = (size_t)c * CL * 64;
  double lg[CL];
  #pragma unroll
  for (int i = 0; i < CL; ++i) lg[i] = lg64[tb + i * 64 + lane];
  #pragma unroll
  for (int i = 0; i < CL; ++i) lgs[wv][i][lane] = lg[i];
  __syncthreads();

  double vn[CL];
  int jn[CL];
  #pragma unroll
  for (int i = 0; i < CL; ++i) { vn[i] = -1.0e300; jn[i] = 0; }
  #pragma unroll 2
  for (int k = 0; k < maxdeg; ++k) {
    int j = nbrTs[k * 64 + lane];
    #pragma unroll
    for (int i = 0; i < CL; ++i) {
      double val = lgs[wv][i][j];
      if (val > vn[i]) { vn[i] = val; jn[i] = j; }  // ascending j, strict >
    }
  }

  int F[CL];
  #pragma unroll
  for (int i = 0; i < CL; ++i) {
    double v = lg[i];
    int idx = lane;
    #pragma unroll
    for (int off = 1; off < 64; off <<= 1) {
      double ov = __shfl_xor(v, off, 64);
      int oi = __shfl_xor(idx, off, 64);
      if (ov > v || (ov == v && oi < idx)) { v = ov; idx = oi; }
    }
    int f;
    if ((mask >> idx) & 1ull) f = idx;
    else {
      double vg = v - 1.0;
      if (vn[i] > vg) f = jn[i];
      else if (vn[i] < vg) f = idx;
      else f = jn[i] < idx ? jn[i] : idx;
    }
    F[i] = f;
  }
  int cur = lane;
  #pragma unroll
  for (int i = 0; i < CL; ++i) cur = __shfl(F[i], cur, 64);
  chunkG[(size_t)c * 64 + lane] = (unsigned char)cur;
}

// ---------------------------------------------------------------------------
// K4: compose SUP_L chunk tables into each super table (unchanged).
// ---------------------------------------------------------------------------
__global__ void super_compose_kernel(const unsigned char* __restrict__ chunkG,
                                     unsigned char* __restrict__ superS) {
  int lane = threadIdx.x & 63, wv = threadIdx.x >> 6;
  int k = blockIdx.x * 4 + wv;
  int cur = lane;
  #pragma unroll 8
  for (int c = k * SUP_L; c < (k + 1) * SUP_L; ++c) {
    int g = chunkG[(size_t)c * 64 + lane];
    cur = __shfl(g, cur, 64);
  }
  superS[(size_t)k * 64 + lane] = (unsigned char)cur;
}

// ---------------------------------------------------------------------------
// K5: sequential walk over NSUPER super tables (unchanged).
// ---------------------------------------------------------------------------
__global__ void super_walk_kernel(const unsigned char* __restrict__ superS,
                                  int* __restrict__ supState) {
  __shared__ unsigned char ssup[NSUPER * 64];
  int lane = threadIdx.x;
  for (int i = lane; i < NSUPER * 16; i += 64)
    ((unsigned int*)ssup)[i] = ((const unsigned int*)superS)[i];
  __syncthreads();
  int s = 0;
  if (lane == 0) supState[0] = 0;
  for (int k = 0; k < NSUPER; ++k) {
    int v = ssup[k * 64 + lane];
    s = __shfl(v, s, 64);
    if (lane == 0 && k + 1 < NSUPER) supState[k + 1] = s;
  }
}

// ---------------------------------------------------------------------------
// K6: per-chunk start states — LDS-staged walk (was a 64-deep dependent
// global-load chain). Coalesced stage, short LDS chain, coalesced store.
// ---------------------------------------------------------------------------
__global__ __launch_bounds__(256) void chunk_states_kernel(
    const unsigned char* __restrict__ chunkG,
    const int* __restrict__ supState,
    int* __restrict__ chunkState) {
  __shared__ unsigned char g[4][SUP_L * 64];
  __shared__ int sbuf[4][SUP_L];
  int tid = threadIdx.x, lane = tid & 63, wv = tid >> 6;
  int k = blockIdx.x * 4 + wv;
  const unsigned int* src = (const unsigned int*)(chunkG + (size_t)k * SUP_L * 64);
  unsigned int* dst = (unsigned int*)g[wv];
  #pragma unroll 4
  for (int i = lane; i < SUP_L * 16; i += 64) dst[i] = src[i];
  // wave-private LDS region; compiler orders the dependent reads
  int s = supState[k];
  for (int c = 0; c < SUP_L; ++c) {
    if (lane == 0) sbuf[wv][c] = s;
    s = g[wv][c * 64 + s];
  }
  chunkState[k * SUP_L + lane] = sbuf[wv][lane];
}

// ---------------------------------------------------------------------------
// K7: finalize (unchanged from round 2).
// ---------------------------------------------------------------------------
__global__ __launch_bounds__(256) void finalize_kernel(
    const double* __restrict__ lg64, const unsigned char* __restrict__ ws_ro,
    const int* __restrict__ chunkState, float* __restrict__ out) {
  __shared__ ull adjs[64];
  int tid = threadIdx.x, lane = tid & 63, wv = tid >> 6;
  if (tid < 64) adjs[tid] = ((const ull*)(ws_ro + ADJ_OFF))[tid];
  __syncthreads();
  int c = blockIdx.x * 4 + wv;
  int s = chunkState[c];
  size_t tb = (size_t)c * CL * 64;
  #pragma unroll
  for (int i = 0; i < CL; ++i) {
    double lg = lg64[tb + i * 64 + lane];
    int bit = (int)((adjs[s] >> lane) & 1ull);
    double v = bit ? lg : lg - 1.0;
    out[tb + i * 64 + lane] = (float)v;
    int idx = lane;
    #pragma unroll
    for (int off = 1; off < 64; off <<= 1) {
      double ov = __shfl_xor(v, off, 64);
      int oi = __shfl_xor(idx, off, 64);
      if (ov > v || (ov == v && oi < idx)) { v = ov; idx = oi; }
    }
    s = idx;  // uniform across lanes
  }
}

// ---------------------------------------------------------------------------
extern "C" void kernel_launch(void* const* d_in, const int* in_sizes, int n_in,
                              void* d_out, int out_size, void* d_ws, size_t ws_size,
                              hipStream_t stream) {
  const float* pa    = (const float*)d_in[0];
  const float* times = (const float*)d_in[1];
  // d_in[2] zone_features: unused by the reference
  const int*   edges = (const int*)d_in[3];
  const float* W1    = (const float*)d_in[4];
  const float* b1    = (const float*)d_in[5];
  const float* W2    = (const float*)d_in[6];
  const float* b2    = (const float*)d_in[7];
  const float* W3    = (const float*)d_in[8];
  const float* b3    = (const float*)d_in[9];

  unsigned char* ws = (unsigned char*)d_ws;
  unsigned char* outb = (unsigned char*)d_out;  // scratch until finalize
  double* lg64 = (double*)(ws + LG64_OFF);
  unsigned char* chunkG = outb + CHUNKG_DOUT;
  unsigned char* superS = outb + SUPERS_DOUT;
  int* supState = (int*)(outb + SUPSTATE_DOUT);
  int* chunkState = (int*)(ws + CHUNKSTATE_OFF);

  hipLaunchKernelGGL(prep_kernel, dim3(1), dim3(512), 0, stream,
                     pa, edges, W1, b1, W2, b2, W3, b3, ws);
  hipLaunchKernelGGL(mlp_kernel, dim3(T_STEPS / 64), dim3(64), 0, stream,
                     times, ws, lg64);
  hipLaunchKernelGGL(chunk_tables_kernel, dim3(NCHUNK / 4), dim3(256), 0, stream,
                     lg64, ws, chunkG);
  hipLaunchKernelGGL(super_compose_kernel, dim3(NSUPER / 4), dim3(256), 0, stream,
                     chunkG, superS);
  hipLaunchKernelGGL(super_walk_kernel, dim3(1), dim3(64), 0, stream,
                     superS, supState);
  hipLaunchKernelGGL(chunk_states_kernel, dim3(NSUPER / 4), dim3(256), 0, stream,
                     chunkG, supState, chunkState);
  hipLaunchKernelGGL(finalize_kernel, dim3(NCHUNK / 4), dim3(256), 0, stream,
                     lg64, ws, chunkState, (float*)d_out);
}